// Round 4
// baseline (162.995 us; speedup 1.0000x reference)
//
#include <hip/hip_runtime.h>
#include <math.h>

#define TOKENS 32768
#define RDIM 512
#define NEXP 64
#define NK 256
#define LDB 264            // w-plane LDS row stride in ushorts (256 + 8 pad); 528B rows -> 2-way banks (free)
#define PSTR 67            // logit plane row stride (words)
#define TAU 4.0e-3f        // top-2/3 boundary guard band (~60x worst-case bf16x3 logit error)

typedef unsigned short u16;
typedef float f32x4 __attribute__((ext_vector_type(4)));
typedef short s16x8 __attribute__((ext_vector_type(8)));

#define MFMA_B16(a, b, c) __builtin_amdgcn_mfma_f32_16x16x32_bf16(a, b, c, 0, 0, 0)

// Truncating hi/lo bf16 split of 4 floats, packed pairwise into uints (k-ascending).
__device__ __forceinline__ void split_pack(float4 v, unsigned& h01, unsigned& h23,
                                           unsigned& l01, unsigned& l23) {
    unsigned u0 = __float_as_uint(v.x), u1 = __float_as_uint(v.y);
    unsigned u2 = __float_as_uint(v.z), u3 = __float_as_uint(v.w);
    float r0 = v.x - __uint_as_float(u0 & 0xFFFF0000u);
    float r1 = v.y - __uint_as_float(u1 & 0xFFFF0000u);
    float r2 = v.z - __uint_as_float(u2 & 0xFFFF0000u);
    float r3 = v.w - __uint_as_float(u3 & 0xFFFF0000u);
    h01 = (u0 >> 16) | (u1 & 0xFFFF0000u);
    h23 = (u2 >> 16) | (u3 & 0xFFFF0000u);
    l01 = (__float_as_uint(r0) >> 16) | (__float_as_uint(r1) & 0xFFFF0000u);
    l23 = (__float_as_uint(r2) >> 16) | (__float_as_uint(r3) & 0xFFFF0000u);
}

// 8 floats -> bf16-hi frag + bf16-lo frag, in registers.
__device__ __forceinline__ void split8(float4 a, float4 b, s16x8& hi, s16x8& lo) {
    union U { unsigned u[4]; s16x8 v; };
    U H, L;
    split_pack(a, H.u[0], H.u[1], L.u[0], L.u[1]);
    split_pack(b, H.u[2], H.u[3], L.u[2], L.u[3]);
    hi = H.v; lo = L.v;
}

// ---------------- Kernel A: expert centroids via sign-LUT bit tricks ----------------
__global__ __launch_bounds__(256) void centroid_kernel(
    const float* __restrict__ atoms,
    const float* __restrict__ cw,
    const float* __restrict__ cl,
    float* __restrict__ cent,
    float* __restrict__ aux_sum,
    unsigned* __restrict__ aux_cnt,
    unsigned* __restrict__ done)
{
    __shared__ unsigned pack[NK];
    const int e    = blockIdx.x >> 1;
    const int half = blockIdx.x & 1;
    const int tid  = threadIdx.x;

    if (blockIdx.x == 0 && tid < 64) { aux_sum[tid] = 0.f; aux_cnt[tid] = 0u; }
    if (done && blockIdx.x == 0 && tid == 0) *done = 0u;

    {   // one k per thread (256 threads == NK)
        const int k = tid;
        unsigned u = 0;
        float w3[3];
        #pragma unroll
        for (int xx = 0; xx < 3; ++xx) {
            const float* cp = cl + ((((size_t)e * NK + k) * 3 + xx) << 4);
            float v[16];
            *(float4*)(v + 0)  = *(const float4*)(cp + 0);
            *(float4*)(v + 4)  = *(const float4*)(cp + 4);
            *(float4*)(v + 8)  = *(const float4*)(cp + 8);
            *(float4*)(v + 12) = *(const float4*)(cp + 12);
            float best = v[0]; int bi = 0;
            #pragma unroll
            for (int a = 1; a < 16; ++a) {          // strict > keeps first max (jnp.argmax)
                if (v[a] > best) { best = v[a]; bi = a; }
            }
            u |= (unsigned)bi << (4 * xx);
            w3[xx] = cw[((size_t)e * NK + k) * 3 + xx];
        }
        unsigned lut = 0;
        #pragma unroll
        for (int c = 0; c < 8; ++c) {
            float val = ((c & 1) ? -w3[0] : w3[0])
                      + ((c & 2) ? -w3[1] : w3[1])
                      + ((c & 4) ? -w3[2] : w3[2]);
            lut |= (val < 0.f ? 1u : 0u) << c;
        }
        pack[k] = u | (lut << 16);
    }

    const int r = half * 256 + tid;
    unsigned B0 = 0;
    #pragma unroll
    for (int a = 0; a < 16; ++a)
        B0 |= (atoms[((size_t)e * 16 + a) * RDIM + r] < 0.f ? 1u : 0u) << a;
    __syncthreads();

    int n0 = 0;
    for (int k = 0; k < NK; ++k) {
        unsigned u  = pack[k];
        unsigned i0 = u & 15u, i1 = (u >> 4) & 15u, i2 = (u >> 8) & 15u;
        unsigned c0 = ((B0 >> i0) & 1u) | (((B0 >> i1) & 1u) << 1) | (((B0 >> i2) & 1u) << 2);
        n0 += (u >> (16 + c0)) & 1u;
    }
    cent[(size_t)e * RDIM + r] = 1.f - (float)n0 * (1.f / 128.f);
}

// ---------------- Kernel B: persistent-tile MFMA GEMM + MoE epilogue + fused aux ----------
// Grid 256 = 1 block/CU. Block = 128 tokens x 64 experts, 512 threads = 8 waves,
// wave w owns tokens w*16..w*16+15 x ALL 64 experts (nt=0..3, acc[4]) -> x read ONCE.
// A-frags straight from global (f32, hi/lo-split in regs, 4-deep prefetch, no barriers).
// w staged in LDS bf16 hi/lo planes per K-half; half-1's loads issued mid half-0 loop.
// Verified MFMA mapping: A row=l15(token), B row=l15(expert), k=(lane>>4)*8+j;
// C col=lane&15 (expert), row=(lane>>4)*4+i (token).
__global__ __launch_bounds__(512, 2) void moe_main(
    const float* __restrict__ x,
    const float* __restrict__ w,
    const float* __restrict__ cent,
    float* __restrict__ out,
    float* __restrict__ aux_sum,
    unsigned* __restrict__ aux_cnt,
    unsigned* __restrict__ done,
    float* __restrict__ out_aux,
    int fuse)
{
    __shared__ u16 wlds[2 * 64 * LDB];     // 67584 B: whi + wlo planes, one K-half at a time
    u16* whi = wlds;
    u16* wlo = wlds + 64 * LDB;
    // epilogue overlays (staging dead by then; 52.2KB used of 67.6KB)
    float* P     = (float*)wlds;                 // [128][PSTR] logits -> probs in place
    float* candv = P + 128 * PSTR;               // [128][13] (4 slices x top-3, padded)
    int*   candi = (int*)(candv + 128 * 13);
    float* qsum  = (float*)(candi + 128 * 13);   // [128][5]
    float* gateL = qsum + 128 * 5;               // [128][4]: g1,g2,bitcast(e1),bitcast(e2)
    __shared__ float s_aux[64];
    __shared__ unsigned s_cnt[64];
    __shared__ int s_last;

    const int tid  = threadIdx.x;
    const int lane = tid & 63;
    const int wave = tid >> 6;
    const int l15  = lane & 15;
    const int kgrp = (lane >> 4) << 3;     // 0,8,16,24
    const int tok0 = blockIdx.x * 128;

    if (tid < 64) { s_aux[tid] = 0.f; s_cnt[tid] = 0u; }

    f32x4 acc[4];
    #pragma unroll
    for (int nt = 0; nt < 4; ++nt) acc[nt] = (f32x4){0.f, 0.f, 0.f, 0.f};

    // A path: lane's own token row
    const float* xlane = x + (size_t)(tok0 + wave * 16 + l15) * RDIM + kgrp;
    // w staging map: thread covers 32 consecutive floats of one expert row
    const int wrow = tid >> 3;             // 0..63
    const int wseg = tid & 7;              // 0..7
    const float* wg = w + (size_t)wrow * RDIM + wseg * 32;
    const int woff = wrow * LDB + wseg * 32;   // ushort offset

    float4 wpre[8];
    #pragma unroll
    for (int j = 0; j < 8; ++j) wpre[j] = *(const float4*)(wg + j * 4);   // w half-0

    float4 preA[4], preB[4];
    #pragma unroll
    for (int i = 0; i < 4; ++i) {          // x steps 0..3
        preA[i] = *(const float4*)(xlane + i * 32);
        preB[i] = *(const float4*)(xlane + i * 32 + 4);
    }

    #pragma unroll
    for (int h = 0; h < 2; ++h) {
        if (h) __syncthreads();            // half-0 B-frag reads done before overwrite
        #pragma unroll
        for (int j = 0; j < 8; ++j) {      // stage w K-half from prefetched regs
            unsigned h01, h23, l01, l23;
            split_pack(wpre[j], h01, h23, l01, l23);
            *(uint2*)&whi[woff + j * 4] = make_uint2(h01, h23);
            *(uint2*)&wlo[woff + j * 4] = make_uint2(l01, l23);
        }
        __syncthreads();

        #pragma unroll
        for (int kb = 0; kb < 8; ++kb) {   // 8 K32 steps, barrier-free, 4-deep x prefetch
            s16x8 ah, al;
            split8(preA[kb & 3], preB[kb & 3], ah, al);
            const int gk = h * 8 + kb + 4;
            if (gk < 16) {                 // continuous pipeline across the half boundary
                const float* nx = xlane + gk * 32;
                preA[kb & 3] = *(const float4*)(nx);
                preB[kb & 3] = *(const float4*)(nx + 4);
            }
            if (h == 0 && kb == 2) {       // issue w half-1 loads; fly across barriers
                #pragma unroll
                for (int j = 0; j < 8; ++j)
                    wpre[j] = *(const float4*)(wg + 256 + j * 4);
            }
            const int kl = kb * 32 + kgrp;
            #pragma unroll
            for (int nt = 0; nt < 4; ++nt) {
                const int brow = nt * 16 + l15;
                s16x8 bh = *(const s16x8*)&whi[brow * LDB + kl];
                s16x8 bl = *(const s16x8*)&wlo[brow * LDB + kl];
                acc[nt] = MFMA_B16(ah, bh, acc[nt]);   // hi*hi
                acc[nt] = MFMA_B16(ah, bl, acc[nt]);   // hi*lo
                acc[nt] = MFMA_B16(al, bh, acc[nt]);   // lo*hi
            }
        }
    }

    // ---- logits to LDS plane [128 tok][PSTR] ----
    __syncthreads();
    #pragma unroll
    for (int nt = 0; nt < 4; ++nt)
        #pragma unroll
        for (int i = 0; i < 4; ++i)
            P[(wave * 16 + ((lane >> 4) << 2) + i) * PSTR + nt * 16 + l15] = acc[nt][i];
    __syncthreads();

    // ---- E1: per (token tt, slice ss) local top-3 over 16 experts ----
    const int tt = tid & 127;
    const int ss = tid >> 7;               // 0..3
    float v[16];
    #pragma unroll
    for (int j = 0; j < 16; ++j) v[j] = P[tt * PSTR + ss * 16 + j];

    float m1 = -INFINITY, m2 = -INFINITY, m3 = -INFINITY;
    int   i1 = NEXP, i2 = NEXP, i3 = NEXP;
    #pragma unroll
    for (int j = 0; j < 16; ++j) {         // ascending e + strict > == lax.top_k tie-break
        float val = v[j]; int e = ss * 16 + j;
        if (val > m1)      { m3 = m2; i3 = i2; m2 = m1; i2 = i1; m1 = val; i1 = e; }
        else if (val > m2) { m3 = m2; i3 = i2; m2 = val; i2 = e; }
        else if (val > m3) { m3 = val; i3 = e; }
    }
    candv[tt * 13 + ss * 3 + 0] = m1; candi[tt * 13 + ss * 3 + 0] = i1;
    candv[tt * 13 + ss * 3 + 1] = m2; candi[tt * 13 + ss * 3 + 1] = i2;
    candv[tt * 13 + ss * 3 + 2] = m3; candi[tt * 13 + ss * 3 + 2] = i3;
    __syncthreads();

    // ---- E2: merge 12 candidates (slice-ascending insertion keeps low-index ties first) ----
    m1 = m2 = m3 = -INFINITY; i1 = i2 = i3 = NEXP;
    #pragma unroll
    for (int q = 0; q < 12; ++q) {
        float val = candv[tt * 13 + q]; int e = candi[tt * 13 + q];
        if (val > m1)      { m3 = m2; i3 = i2; m2 = m1; i2 = i1; m1 = val; i1 = e; }
        else if (val > m2) { m3 = m2; i3 = i2; m2 = val; i2 = e; }
        else if (val > m3) { m3 = val; i3 = e; }
    }

    float ex[16]; float ps = 0.f;
    #pragma unroll
    for (int j = 0; j < 16; ++j) { ex[j] = __expf(v[j] - m1); ps += ex[j]; }
    qsum[tt * 5 + ss] = ps;

    if (ss == 0) {                         // waves 0-1: gates + cooperative guard re-rank
        {   // default gates from MFMA logits
            const float ed  = __expf(m2 - m1);
            const float inv = 1.f / (1.f + ed);
            gateL[tt * 4 + 0] = inv;
            gateL[tt * 4 + 1] = ed * inv;
            ((int*)gateL)[tt * 4 + 2] = i1;
            ((int*)gateL)[tt * 4 + 3] = i2;
        }
        const int tbase = wave << 6;       // wave 0 -> tokens 0-63, wave 1 -> 64-127
        unsigned long long bmask = __ballot(m2 - m3 < TAU);
        while (bmask) {
            const int f = __ffsll(bmask) - 1;
            bmask &= bmask - 1;
            int id3[3];
            id3[0] = __shfl(i1, f); id3[1] = __shfl(i2, f); id3[2] = __shfl(i3, f);
            const float* xrow = x + (size_t)(tok0 + tbase + f) * RDIM + lane * 8;
            float4 a0 = *(const float4*)(xrow);
            float4 a1 = *(const float4*)(xrow + 4);
            float d[3];
            #pragma unroll
            for (int jj = 0; jj < 3; ++jj) {
                const float* wrow = w + (size_t)id3[jj] * RDIM + lane * 8;
                float4 b0 = *(const float4*)(wrow);
                float4 b1 = *(const float4*)(wrow + 4);
                float p = a0.x * b0.x;
                p = fmaf(a0.y, b0.y, p); p = fmaf(a0.z, b0.z, p); p = fmaf(a0.w, b0.w, p);
                p = fmaf(a1.x, b1.x, p); p = fmaf(a1.y, b1.y, p);
                p = fmaf(a1.z, b1.z, p); p = fmaf(a1.w, b1.w, p);
                #pragma unroll
                for (int off = 32; off; off >>= 1) p += __shfl_xor(p, off);
                d[jj] = p;
            }
            int b = 0;
            if (d[1] > d[0] || (d[1] == d[0] && id3[1] < id3[0])) b = 1;
            if (d[2] > d[b] || (d[2] == d[b] && id3[2] < id3[b])) b = 2;
            int sec;
            if (b == 0)      sec = (d[1] > d[2] || (d[1] == d[2] && id3[1] < id3[2])) ? 1 : 2;
            else if (b == 1) sec = (d[0] > d[2] || (d[0] == d[2] && id3[0] < id3[2])) ? 0 : 2;
            else             sec = (d[0] > d[1] || (d[0] == d[1] && id3[0] < id3[1])) ? 0 : 1;
            if (lane == f) {
                const float ed  = __expf(d[sec] - d[b]);
                const float inv = 1.f / (1.f + ed);
                gateL[(tbase + f) * 4 + 0] = inv;
                gateL[(tbase + f) * 4 + 1] = ed * inv;
                ((int*)gateL)[(tbase + f) * 4 + 2] = id3[b];
                ((int*)gateL)[(tbase + f) * 4 + 3] = id3[sec];
            }
        }
    }
    __syncthreads();

    // ---- E3: softmax denominator + probs in place ----
    float Z = 0.f;
    #pragma unroll
    for (int k = 0; k < 4; ++k) Z += qsum[tt * 5 + k];
    const float invZ = 1.f / Z;
    #pragma unroll
    for (int j = 0; j < 16; ++j) P[tt * PSTR + ss * 16 + j] = ex[j] * invZ;
    __syncthreads();

    // ---- E4: per-expert column sums for aux ----
    {
        const int e = tid & 63, tq = tid >> 6;     // 8 token-groups of 16
        float s = 0.f; unsigned cn = 0u;
        #pragma unroll
        for (int t = 0; t < 16; ++t) {
            float pv = P[(tq * 16 + t) * PSTR + e];
            s += pv; cn += (pv > 0.f) ? 1u : 0u;
        }
        atomicAdd(&s_aux[e], s);
        atomicAdd(&s_cnt[e], cn);
    }
    __syncthreads();
    if (tid < 64) {
        atomicAdd(aux_sum + tid, s_aux[tid]);
        atomicAdd(aux_cnt + tid, s_cnt[tid]);
    }

    // ---- OUT: wave handles 16 tokens, lane = r-chunk (coalesced 1KB stores) ----
    {
        const int e = lane;
        #pragma unroll
        for (int s2 = 0; s2 < 16; ++s2) {
            const int t2 = wave * 16 + s2;
            float4 g4 = *(float4*)&gateL[t2 * 4];       // broadcast read
            const float g1 = g4.x, g2 = g4.y;
            const int e1 = __float_as_int(g4.z), e2 = __float_as_int(g4.w);
            const float4* c1 = (const float4*)(cent + (size_t)e1 * RDIM);
            const float4* c2 = (const float4*)(cent + (size_t)e2 * RDIM);
            float4* op = (float4*)(out + (size_t)(tok0 + t2) * RDIM);
            float4 A0 = c1[e],      Bb0 = c2[e];
            float4 A1 = c1[e + 64], Bb1 = c2[e + 64];
            float4 o0, o1;
            o0.x = fmaf(g1, A0.x, g2 * Bb0.x); o0.y = fmaf(g1, A0.y, g2 * Bb0.y);
            o0.z = fmaf(g1, A0.z, g2 * Bb0.z); o0.w = fmaf(g1, A0.w, g2 * Bb0.w);
            o1.x = fmaf(g1, A1.x, g2 * Bb1.x); o1.y = fmaf(g1, A1.y, g2 * Bb1.y);
            o1.z = fmaf(g1, A1.z, g2 * Bb1.z); o1.w = fmaf(g1, A1.w, g2 * Bb1.w);
            op[e]      = o0;
            op[e + 64] = o1;
        }
    }

    // ---- fused aux finalize: last block to finish reduces the global accumulators ----
    if (fuse) {
        __syncthreads();                   // barrier drains this block's global atomics
        if (tid == 0) {
            __threadfence();
            s_last = (atomicAdd(done, 1u) == 255u) ? 1 : 0;
        }
        __syncthreads();
        if (s_last && tid < 64) {
            float    sv = atomicAdd(&aux_sum[tid], 0.f);    // atomic read-back
            unsigned cv = atomicAdd(&aux_cnt[tid], 0u);
            float val = (sv * (1.f / (float)TOKENS)) * ((float)cv * (1.f / (float)TOKENS));
            #pragma unroll
            for (int off = 32; off; off >>= 1) val += __shfl_xor(val, off);
            if (tid == 0) out_aux[0] = (float)NEXP * val;
        }
    }
}

// ---------------- Kernel C: aux loss finalize (fallback when ws too small to fuse) ----------
__global__ __launch_bounds__(64) void aux_kernel(
    const float* __restrict__ sums,
    const unsigned* __restrict__ cnts,
    float* __restrict__ out_aux)
{
    const int e = threadIdx.x;
    float v = (sums[e] * (1.f / (float)TOKENS)) * ((float)cnts[e] * (1.f / (float)TOKENS));
    #pragma unroll
    for (int off = 32; off; off >>= 1) v += __shfl_xor(v, off);
    if (e == 0) out_aux[0] = (float)NEXP * v;
}

extern "C" void kernel_launch(void* const* d_in, const int* in_sizes, int n_in,
                              void* d_out, int out_size, void* d_ws, size_t ws_size,
                              hipStream_t stream) {
    const float* x     = (const float*)d_in[0];  // (8,4096,512)
    const float* rw    = (const float*)d_in[1];  // (64,512)
    const float* atoms = (const float*)d_in[2];  // (64,16,512)
    const float* cwts  = (const float*)d_in[3];  // (64,256,3)
    const float* clog  = (const float*)d_in[4];  // (64,256,3,16)
    float* out = (float*)d_out;

    const bool fused = ws_size >= (size_t)(1024 + NEXP * RDIM * 4);
    float*    aux_sum = (float*)d_ws;                                   // 64 floats @0
    unsigned* aux_cnt = (unsigned*)((char*)d_ws + 256);                 // 64 uints @256
    unsigned* done    = fused ? (unsigned*)((char*)d_ws + 512) : nullptr;
    float*    cent    = (float*)((char*)d_ws + (fused ? 1024 : 512));   // 64*512 floats

    centroid_kernel<<<128, 256, 0, stream>>>(atoms, cwts, clog, cent, aux_sum, aux_cnt, done);
    moe_main<<<256, 512, 0, stream>>>(x, rw, cent, out, aux_sum, aux_cnt, done,
                                      out + (size_t)TOKENS * RDIM, fused ? 1 : 0);
    if (!fused)
        aux_kernel<<<1, 64, 0, stream>>>(aux_sum, aux_cnt, out + (size_t)TOKENS * RDIM);
}